// Round 2
// baseline (509.336 us; speedup 1.0000x reference)
//
#include <hip/hip_runtime.h>

typedef short bf16x8 __attribute__((ext_vector_type(8)));
typedef float f32x4 __attribute__((ext_vector_type(4)));
typedef int i32x4v __attribute__((ext_vector_type(4)));

#define LOG2E 1.44269504088896340736f
#define INV_SCALE 0.03608439182435161f        /* 1/sqrt(768) */
#define Q_PRESCALE 0.05205877485199535f        /* LOG2E/sqrt(768) */

__device__ __forceinline__ unsigned short f2bf(float f) {
  unsigned u = __float_as_uint(f);
  u += 0x7fffu + ((u >> 16) & 1u);   // round-to-nearest-even
  return (unsigned short)(u >> 16);
}

__device__ __forceinline__ void gload_lds16(const void* g, void* l) {
  __builtin_amdgcn_global_load_lds(
      (const __attribute__((address_space(1))) void*)g,
      (__attribute__((address_space(3))) void*)l, 16, 0, 0);
}

__global__ __launch_bounds__(256) void f2bf_kernel(const float* __restrict__ src,
                                                   unsigned short* __restrict__ dst,
                                                   int n4) {
  int i = blockIdx.x * blockDim.x + threadIdx.x;
  if (i < n4) {
    float4 v = ((const float4*)src)[i];
    ushort4 o;
    o.x = f2bf(v.x); o.y = f2bf(v.y); o.z = f2bf(v.z); o.w = f2bf(v.w);
    ((ushort4*)dst)[i] = o;
  }
}

// C = A[M][K] * B[N][K]^T, bf16 in, fp32 acc. 128x128 tile, BK=32, 4 waves (2x2 of 64x64).
// EPI=0: QKV epilogue (bias, scale Q by LOG2E/sqrt(768), scatter to Q/K/VT).  EPI=1: proj epilogue.
template<int EPI>
__global__ __launch_bounds__(256) void gemm_bt(
    const unsigned short* __restrict__ A,
    const unsigned short* __restrict__ B,
    const float* __restrict__ bias,
    void* __restrict__ out0,
    unsigned short* __restrict__ Kb,
    unsigned short* __restrict__ VTb) {
  constexpr int K = 768;
  __shared__ unsigned short Alds[128 * 32];
  __shared__ unsigned short Blds[128 * 32];
  const int tid = threadIdx.x;
  const int w = tid >> 6, lane = tid & 63;
  const int g = lane >> 4, qq = lane & 15;
  const int wr = w >> 1, wc = w & 1;
  const int mbase = blockIdx.y * 128;
  const int nbase = blockIdx.x * 128;
  const unsigned short* Ab = A + (size_t)mbase * K;
  const unsigned short* Bb = B + (size_t)nbase * K;

  f32x4 acc[4][4];
#pragma unroll
  for (int i = 0; i < 4; i++)
#pragma unroll
    for (int j = 0; j < 4; j++) acc[i][j] = (f32x4){0.f, 0.f, 0.f, 0.f};

  const int idx0 = (w * 2) * 64 + lane;      // 0..511 chunk ids (16B each)
  const int idx1 = (w * 2 + 1) * 64 + lane;
  const int r0 = idx0 >> 2, c0 = idx0 & 3;
  const int r1 = idx1 >> 2, c1 = idx1 & 3;

  for (int k0 = 0; k0 < K; k0 += 32) {
    __syncthreads();
    gload_lds16(Ab + (size_t)r0 * K + k0 + c0 * 8, &Alds[idx0 * 8]);
    gload_lds16(Ab + (size_t)r1 * K + k0 + c1 * 8, &Alds[idx1 * 8]);
    gload_lds16(Bb + (size_t)r0 * K + k0 + c0 * 8, &Blds[idx0 * 8]);
    gload_lds16(Bb + (size_t)r1 * K + k0 + c1 * 8, &Blds[idx1 * 8]);
    __syncthreads();
    bf16x8 af[4], bfr[4];
#pragma unroll
    for (int mi = 0; mi < 4; mi++)
      af[mi] = *(const bf16x8*)&Alds[(wr * 64 + mi * 16 + qq) * 32 + g * 8];
#pragma unroll
    for (int ni = 0; ni < 4; ni++)
      bfr[ni] = *(const bf16x8*)&Blds[(wc * 64 + ni * 16 + qq) * 32 + g * 8];
#pragma unroll
    for (int mi = 0; mi < 4; mi++)
#pragma unroll
      for (int ni = 0; ni < 4; ni++)
        acc[mi][ni] = __builtin_amdgcn_mfma_f32_16x16x32_bf16(af[mi], bfr[ni], acc[mi][ni], 0, 0, 0);
  }

  const int colb = nbase + wc * 64;
  const int rowb = mbase + wr * 64;
  if (EPI == 0) {
    unsigned short* Qb = (unsigned short*)out0;
#pragma unroll
    for (int ni = 0; ni < 4; ni++) {
      const int col = colb + ni * 16 + qq;        // col = h*192 + d*3 + c
      const float bv = bias[col];
      const int c = col % 3;
      const int dd = (col / 3) & 63;
      const int h = col / 192;
#pragma unroll
      for (int mi = 0; mi < 4; mi++)
#pragma unroll
        for (int r = 0; r < 4; r++) {
          const int row = rowb + mi * 16 + g * 4 + r;   // b*1024 + n
          const int b = row >> 10, n = row & 1023;
          const float v = acc[mi][ni][r] + bv;
          const size_t bh = (size_t)(b * 12 + h);
          if (c == 0)      ((unsigned short*)Qb)[(bh * 1024 + n) * 64 + dd] = f2bf(v * Q_PRESCALE);
          else if (c == 1) Kb[(bh * 1024 + n) * 64 + dd] = f2bf(v);
          else             VTb[(bh * 64 + dd) * 1024 + n] = f2bf(v);
        }
    }
  } else {
    float* O = (float*)out0;
#pragma unroll
    for (int ni = 0; ni < 4; ni++) {
      const int col = colb + ni * 16 + qq;
      const float bv = bias[col];
#pragma unroll
      for (int mi = 0; mi < 4; mi++)
#pragma unroll
        for (int r = 0; r < 4; r++) {
          const int row = rowb + mi * 16 + g * 4 + r;
          O[(size_t)row * 768 + col] = acc[mi][ni][r] + bv;
        }
    }
  }
}

// Flash attention, swapped-operand structure, no LDS, no barriers.
// Each wave owns 16 q-rows (q = q0 + lane&15). S^T = mfma(K, Q^T): lane holds 16 token
// scores for ONE q-row. Softmax in-register (in-lane reduce + 2 shfl_xor over groups).
// P packed to bf16 in-register (cvt_pk) and redistributed into PV B-fragments via shfl.
// O^T = mfma(V^T, P^T): corr/m/l are lane-uniform scalars.
__global__ __launch_bounds__(256) void attn_kernel(
    const unsigned short* __restrict__ Qb,
    const unsigned short* __restrict__ Kb,
    const unsigned short* __restrict__ VTb,
    unsigned short* __restrict__ AO) {
  const int tid = threadIdx.x;
  const int w = tid >> 6, lane = tid & 63;
  const int qq = lane & 15;
  const int G = lane >> 4;
  const bool g5 = (lane >= 32);
  const int bh = blockIdx.y;
  const int b = bh / 12, h = bh % 12;
  const int q0 = blockIdx.x * 64 + w * 16;
  const unsigned short* Qh = Qb + (size_t)bh * 65536;
  const unsigned short* Kh = Kb + (size_t)bh * 65536;
  const unsigned short* Vh = VTb + (size_t)bh * 65536;

  // Q^T B-fragments: lane holds Q[q0+qq][kk*32 + G*8 .. +7]  (pre-scaled by LOG2E/sqrt(768))
  bf16x8 qf[2];
#pragma unroll
  for (int kk = 0; kk < 2; kk++)
    qf[kk] = *(const bf16x8*)&Qh[(size_t)(q0 + qq) * 64 + kk * 32 + G * 8];

  float m_run = -INFINITY, l_run = 0.f;
  f32x4 o[4];
#pragma unroll
  for (int nd = 0; nd < 4; nd++) o[nd] = (f32x4){0.f, 0.f, 0.f, 0.f};

  const int src0 = qq + ((G & 1) << 5);   // source lane, group G' = 2*(G&1)
  const int src1 = src0 + 16;             // group G' = 2*(G&1)+1

  for (int t0 = 0; t0 < 1024; t0 += 64) {
    // S^T = K * Q^T : A-frag = K rows (tok = t0+ni*16+qq, d-slice kk*32+G*8)
    f32x4 s[4];
#pragma unroll
    for (int ni = 0; ni < 4; ni++) s[ni] = (f32x4){0.f, 0.f, 0.f, 0.f};
    const unsigned short* Kt = Kh + (size_t)t0 * 64;
#pragma unroll
    for (int ni = 0; ni < 4; ni++)
#pragma unroll
      for (int kk = 0; kk < 2; kk++) {
        bf16x8 ka = *(const bf16x8*)&Kt[(ni * 16 + qq) * 64 + kk * 32 + G * 8];
        s[ni] = __builtin_amdgcn_mfma_f32_16x16x32_bf16(ka, qf[kk], s[ni], 0, 0, 0);
      }

    // V^T A-fragments for this tile (hoisted: independent of softmax, hides latency)
    bf16x8 vf[4][2];
    const unsigned short* Vt = Vh + t0;
#pragma unroll
    for (int nd = 0; nd < 4; nd++)
#pragma unroll
      for (int kk = 0; kk < 2; kk++)
        vf[nd][kk] = *(const bf16x8*)&Vt[(size_t)(nd * 16 + qq) * 1024 + kk * 32 + G * 8];

    // ---- online softmax (scores already in log2 units) ----
    float mx = s[0][0];
#pragma unroll
    for (int ni = 0; ni < 4; ni++)
#pragma unroll
      for (int r = 0; r < 4; r++) mx = fmaxf(mx, s[ni][r]);
    mx = fmaxf(mx, __shfl_xor(mx, 16));
    mx = fmaxf(mx, __shfl_xor(mx, 32));

    if (!__all(mx <= m_run + 11.0f)) {   // defer-max: rescale only on real growth
      const float nm = fmaxf(m_run, mx);
      const float corr = exp2f(m_run - nm);
      m_run = nm;
      l_run *= corr;
#pragma unroll
      for (int nd = 0; nd < 4; nd++)
#pragma unroll
        for (int r = 0; r < 4; r++) o[nd][r] *= corr;
    }

    float rs = 0.f;
#pragma unroll
    for (int ni = 0; ni < 4; ni++)
#pragma unroll
      for (int r = 0; r < 4; r++) {
        s[ni][r] = exp2f(s[ni][r] - m_run);
        rs += s[ni][r];
      }
    rs += __shfl_xor(rs, 16);
    rs += __shfl_xor(rs, 32);
    l_run += rs;

    // ---- pack P to bf16 pairs in-register ----
    int pk0[2], pk1[2], pk2[2], pk3[2];
#pragma unroll
    for (int j = 0; j < 2; j++) {
      asm("v_cvt_pk_bf16_f32 %0, %1, %2" : "=v"(pk0[j]) : "v"(s[0][2 * j]), "v"(s[0][2 * j + 1]));
      asm("v_cvt_pk_bf16_f32 %0, %1, %2" : "=v"(pk1[j]) : "v"(s[1][2 * j]), "v"(s[1][2 * j + 1]));
      asm("v_cvt_pk_bf16_f32 %0, %1, %2" : "=v"(pk2[j]) : "v"(s[2][2 * j]), "v"(s[2][2 * j + 1]));
      asm("v_cvt_pk_bf16_f32 %0, %1, %2" : "=v"(pk3[j]) : "v"(s[3][2 * j]), "v"(s[3][2 * j + 1]));
    }

    // ---- redistribute into PV B-fragments ----
    // frag kk word w (w=j+2b): value pk[2kk + g5][j] from lane qq + 32*(G&1) + 16*b
    i32x4v pw0, pw1;
    {
      int va, vb;
      va = __shfl(pk0[0], src0); vb = __shfl(pk1[0], src0); pw0[0] = g5 ? vb : va;
      va = __shfl(pk0[1], src0); vb = __shfl(pk1[1], src0); pw0[1] = g5 ? vb : va;
      va = __shfl(pk0[0], src1); vb = __shfl(pk1[0], src1); pw0[2] = g5 ? vb : va;
      va = __shfl(pk0[1], src1); vb = __shfl(pk1[1], src1); pw0[3] = g5 ? vb : va;
      va = __shfl(pk2[0], src0); vb = __shfl(pk3[0], src0); pw1[0] = g5 ? vb : va;
      va = __shfl(pk2[1], src0); vb = __shfl(pk3[1], src0); pw1[1] = g5 ? vb : va;
      va = __shfl(pk2[0], src1); vb = __shfl(pk3[0], src1); pw1[2] = g5 ? vb : va;
      va = __shfl(pk2[1], src1); vb = __shfl(pk3[1], src1); pw1[3] = g5 ? vb : va;
    }
    union U { i32x4v i; bf16x8 h; };
    U u0, u1; u0.i = pw0; u1.i = pw1;

    // ---- O^T += V^T * P^T ----
#pragma unroll
    for (int nd = 0; nd < 4; nd++) {
      o[nd] = __builtin_amdgcn_mfma_f32_16x16x32_bf16(vf[nd][0], u0.h, o[nd], 0, 0, 0);
      o[nd] = __builtin_amdgcn_mfma_f32_16x16x32_bf16(vf[nd][1], u1.h, o[nd], 0, 0, 0);
    }
  }

  const float inv_l = 1.0f / l_run;
  const size_t rowbase = (size_t)(b * 1024 + q0 + qq) * 768 + h * 64 + G * 4;
#pragma unroll
  for (int nd = 0; nd < 4; nd++) {
    ushort4 vv;
    vv.x = f2bf(o[nd][0] * inv_l);
    vv.y = f2bf(o[nd][1] * inv_l);
    vv.z = f2bf(o[nd][2] * inv_l);
    vv.w = f2bf(o[nd][3] * inv_l);
    *(ushort4*)&AO[rowbase + nd * 16] = vv;
  }
}

extern "C" void kernel_launch(void* const* d_in, const int* in_sizes, int n_in,
                              void* d_out, int out_size, void* d_ws, size_t ws_size,
                              hipStream_t stream) {
  const float* x      = (const float*)d_in[0];
  const float* w_qkv  = (const float*)d_in[1];
  const float* b_qkv  = (const float*)d_in[2];
  const float* w_proj = (const float*)d_in[3];
  const float* b_proj = (const float*)d_in[4];

  char* ws = (char*)d_ws;
  unsigned short* xb     = (unsigned short*)(ws);               // 25165824 B
  unsigned short* Qb     = (unsigned short*)(ws + 25165824);    // 25165824 B
  unsigned short* Kb     = (unsigned short*)(ws + 50331648);    // 25165824 B
  unsigned short* VTb    = (unsigned short*)(ws + 75497472);    // 25165824 B
  unsigned short* wqkvb  = (unsigned short*)(ws + 100663296);   // 3538944 B
  unsigned short* wprojb = (unsigned short*)(ws + 104202240);   // 1179648 B
  unsigned short* AO = xb;  // alias: xb dead after GEMM1

  f2bf_kernel<<<12288, 256, 0, stream>>>(x, xb, 3145728);
  f2bf_kernel<<<1728, 256, 0, stream>>>(w_qkv, wqkvb, 442368);
  f2bf_kernel<<<576, 256, 0, stream>>>(w_proj, wprojb, 147456);

  gemm_bt<0><<<dim3(18, 128), 256, 0, stream>>>(xb, wqkvb, b_qkv, (void*)Qb, Kb, VTb);
  attn_kernel<<<dim3(16, 192), 256, 0, stream>>>(Qb, Kb, VTb, AO);
  gemm_bt<1><<<dim3(6, 128), 256, 0, stream>>>(AO, wprojb, b_proj, d_out, nullptr, nullptr);
}

// Round 4
// 275.977 us; speedup vs baseline: 1.8456x; 1.8456x over previous
//
#include <hip/hip_runtime.h>

typedef short bf16x8 __attribute__((ext_vector_type(8)));
typedef float f32x4 __attribute__((ext_vector_type(4)));
typedef float f32x16 __attribute__((ext_vector_type(16)));

#define Q_PRESCALE 0.05205877485199535f        /* LOG2E/sqrt(768) */

__device__ __forceinline__ unsigned short f2bf(float f) {
  unsigned u = __float_as_uint(f);
  u += 0x7fffu + ((u >> 16) & 1u);   // round-to-nearest-even
  return (unsigned short)(u >> 16);
}

__device__ __forceinline__ void gload_lds16(const void* g, void* l) {
  __builtin_amdgcn_global_load_lds(
      (const __attribute__((address_space(1))) void*)g,
      (__attribute__((address_space(3))) void*)l, 16, 0, 0);
}

__global__ __launch_bounds__(256) void f2bf_kernel(const float* __restrict__ src,
                                                   unsigned short* __restrict__ dst,
                                                   int n4) {
  int i = blockIdx.x * blockDim.x + threadIdx.x;
  if (i < n4) {
    float4 v = ((const float4*)src)[i];
    ushort4 o;
    o.x = f2bf(v.x); o.y = f2bf(v.y); o.z = f2bf(v.z); o.w = f2bf(v.w);
    ((ushort4*)dst)[i] = o;
  }
}

// C = A[M][K] * B[N][K]^T, bf16 in, fp32 acc. 128x128 tile, BK=32, 4 waves (2x2 of 64x64).
// EPI=0: QKV epilogue (bias, scale Q by LOG2E/sqrt(768), scatter to Q/K/VT).  EPI=1: proj epilogue.
template<int EPI>
__global__ __launch_bounds__(256) void gemm_bt(
    const unsigned short* __restrict__ A,
    const unsigned short* __restrict__ B,
    const float* __restrict__ bias,
    void* __restrict__ out0,
    unsigned short* __restrict__ Kb,
    unsigned short* __restrict__ VTb) {
  constexpr int K = 768;
  __shared__ unsigned short Alds[128 * 32];
  __shared__ unsigned short Blds[128 * 32];
  const int tid = threadIdx.x;
  const int w = tid >> 6, lane = tid & 63;
  const int g = lane >> 4, qq = lane & 15;
  const int wr = w >> 1, wc = w & 1;
  const int mbase = blockIdx.y * 128;
  const int nbase = blockIdx.x * 128;
  const unsigned short* Ab = A + (size_t)mbase * K;
  const unsigned short* Bb = B + (size_t)nbase * K;

  f32x4 acc[4][4];
#pragma unroll
  for (int i = 0; i < 4; i++)
#pragma unroll
    for (int j = 0; j < 4; j++) acc[i][j] = (f32x4){0.f, 0.f, 0.f, 0.f};

  const int idx0 = (w * 2) * 64 + lane;      // 0..511 chunk ids (16B each)
  const int idx1 = (w * 2 + 1) * 64 + lane;
  const int r0 = idx0 >> 2, c0 = idx0 & 3;
  const int r1 = idx1 >> 2, c1 = idx1 & 3;

  for (int k0 = 0; k0 < K; k0 += 32) {
    __syncthreads();
    gload_lds16(Ab + (size_t)r0 * K + k0 + c0 * 8, &Alds[idx0 * 8]);
    gload_lds16(Ab + (size_t)r1 * K + k0 + c1 * 8, &Alds[idx1 * 8]);
    gload_lds16(Bb + (size_t)r0 * K + k0 + c0 * 8, &Blds[idx0 * 8]);
    gload_lds16(Bb + (size_t)r1 * K + k0 + c1 * 8, &Blds[idx1 * 8]);
    __syncthreads();
    bf16x8 af[4], bfr[4];
#pragma unroll
    for (int mi = 0; mi < 4; mi++)
      af[mi] = *(const bf16x8*)&Alds[(wr * 64 + mi * 16 + qq) * 32 + g * 8];
#pragma unroll
    for (int ni = 0; ni < 4; ni++)
      bfr[ni] = *(const bf16x8*)&Blds[(wc * 64 + ni * 16 + qq) * 32 + g * 8];
#pragma unroll
    for (int mi = 0; mi < 4; mi++)
#pragma unroll
      for (int ni = 0; ni < 4; ni++)
        acc[mi][ni] = __builtin_amdgcn_mfma_f32_16x16x32_bf16(af[mi], bfr[ni], acc[mi][ni], 0, 0, 0);
  }

  const int colb = nbase + wc * 64;
  const int rowb = mbase + wr * 64;
  if (EPI == 0) {
    unsigned short* Qb = (unsigned short*)out0;
#pragma unroll
    for (int ni = 0; ni < 4; ni++) {
      const int col = colb + ni * 16 + qq;        // col = h*192 + d*3 + c
      const float bv = bias[col];
      const int c = col % 3;
      const int dd = (col / 3) & 63;
      const int h = col / 192;
#pragma unroll
      for (int mi = 0; mi < 4; mi++)
#pragma unroll
        for (int r = 0; r < 4; r++) {
          const int row = rowb + mi * 16 + g * 4 + r;   // b*1024 + n
          const int b = row >> 10, n = row & 1023;
          const float v = acc[mi][ni][r] + bv;
          const size_t bh = (size_t)(b * 12 + h);
          if (c == 0)      ((unsigned short*)Qb)[(bh * 1024 + n) * 64 + dd] = f2bf(v * Q_PRESCALE);
          else if (c == 1) Kb[(bh * 1024 + n) * 64 + dd] = f2bf(v);
          else             VTb[(bh * 64 + dd) * 1024 + n] = f2bf(v);
        }
    }
  } else {
    float* O = (float*)out0;
#pragma unroll
    for (int ni = 0; ni < 4; ni++) {
      const int col = colb + ni * 16 + qq;
      const float bv = bias[col];
#pragma unroll
      for (int mi = 0; mi < 4; mi++)
#pragma unroll
        for (int r = 0; r < 4; r++) {
          const int row = rowb + mi * 16 + g * 4 + r;
          O[(size_t)row * 768 + col] = acc[mi][ni][r] + bv;
        }
    }
  }
}

// Flash attention: 4 waves x 32 q-rows = 128 q/block, KVBLK=64, 32x32x16 MFMA.
// S^T = mfma(K, Q^T): q-row is lane-local (col = lane&31), 32 token scores split
// across the hi=0/hi=1 lane pair. Softmax in-register (31 fmax + 1 shfl_xor(32)).
// P -> bf16 B-frags via cvt_pk + permlane32_swap(vdst=low-token pack, vsrc=high-token
// pack: exchanges vdst.hi-lanes <-> vsrc.lo-lanes). O^T = mfma(V^T, P^T).
// K/V^T tiles double-buffered in LDS via global_load_lds with inverse-swizzled source:
// slot = chunk ^ (row&7) ^ ((row>>2)&6)  (linear dest, swizzle on both source & read).
__global__ __launch_bounds__(256) void attn_kernel(
    const unsigned short* __restrict__ Qb,
    const unsigned short* __restrict__ Kb,
    const unsigned short* __restrict__ VTb,
    unsigned short* __restrict__ AO) {
  __shared__ unsigned short Klds[2][4096];
  __shared__ unsigned short Vlds[2][4096];
  const int tid = threadIdx.x;
  const int w = tid >> 6, lane = tid & 63;
  const int ql = lane & 31, hi = lane >> 5;

  // XCD-clustered remap: 24 heads per XCD (round-robin bid->XCD assumption, perf-only)
  const int bid = blockIdx.x;
  const int xcd = bid & 7, jj = bid >> 3;
  const int bh = xcd * 24 + (jj >> 3);
  const int qb = jj & 7;
  const int b = bh / 12, h = bh % 12;
  const int q0w = qb * 128 + w * 32;

  const unsigned short* Qh = Qb + (size_t)bh * 65536;
  const unsigned short* Kh = Kb + (size_t)bh * 65536;
  const unsigned short* Vh = VTb + (size_t)bh * 65536;

  // Q^T B-fragments: lane holds Q[q0w+ql][ks*16 + hi*8 .. +7]  (pre-scaled by LOG2E/sqrt(768))
  bf16x8 qf[4];
#pragma unroll
  for (int ks = 0; ks < 4; ++ks)
    qf[ks] = *(const bf16x8*)&Qh[(size_t)(q0w + ql) * 64 + ks * 16 + hi * 8];

  float m_run = -INFINITY, l_run = 0.f;
  f32x16 o[2];
#pragma unroll
  for (int dt = 0; dt < 2; ++dt)
#pragma unroll
    for (int i = 0; i < 16; ++i) o[dt][i] = 0.f;

  // staging geometry: chunk j (16B): row r = j>>3, slot s = j&7; source chunk = s ^ swz(r)
  const int j0 = w * 64 + lane;              // this lane stages chunks j0 and j0+256
  const int r0 = j0 >> 3, s0 = j0 & 7;
  const int g0 = s0 ^ (r0 & 7) ^ ((r0 >> 2) & 6);
  const int r1 = r0 + 32;                    // same slot, same XOR bits -> same g0
  // reader swizzle bits (row = tt*32 + ql: tt doesn't affect the XOR)
  const int sx = (ql & 7) ^ ((ql >> 2) & 6);

  auto stage = [&](int sb, int t0) {
    gload_lds16(Kh + (size_t)(t0 + r0) * 64 + g0 * 8, &Klds[sb][j0 * 8]);
    gload_lds16(Kh + (size_t)(t0 + r1) * 64 + g0 * 8, &Klds[sb][j0 * 8 + 2048]);
    gload_lds16(Vh + (size_t)r0 * 1024 + t0 + g0 * 8, &Vlds[sb][j0 * 8]);
    gload_lds16(Vh + (size_t)r1 * 1024 + t0 + g0 * 8, &Vlds[sb][j0 * 8 + 2048]);
  };

  int buf = 0;
  stage(0, 0);

  for (int t = 0; t < 16; ++t) {
    asm volatile("s_waitcnt vmcnt(0)" ::: "memory");  // staged tile landed
    __syncthreads();
    if (t < 15) stage(buf ^ 1, (t + 1) * 64);         // prefetch next (stays in flight)

    const char* Kbuf = (const char*)&Klds[buf][0];
    const char* Vbuf = (const char*)&Vlds[buf][0];

    // ---- S^T = K * Q^T ----
    f32x16 s[2];
#pragma unroll
    for (int tt = 0; tt < 2; ++tt) {
#pragma unroll
      for (int i = 0; i < 16; ++i) s[tt][i] = 0.f;
#pragma unroll
      for (int ks = 0; ks < 4; ++ks) {
        bf16x8 ka = *(const bf16x8*)(Kbuf + (tt * 32 + ql) * 128 + (((ks * 2 + hi) ^ sx) * 16));
        s[tt] = __builtin_amdgcn_mfma_f32_32x32x16_bf16(ka, qf[ks], s[tt], 0, 0, 0);
      }
    }

    // ---- online softmax (scores in log2 units), q-row = lane pair (ql, ql+32) ----
    float mx = s[0][0];
#pragma unroll
    for (int i = 1; i < 16; ++i) mx = fmaxf(mx, s[0][i]);
#pragma unroll
    for (int i = 0; i < 16; ++i) mx = fmaxf(mx, s[1][i]);
    mx = fmaxf(mx, __shfl_xor(mx, 32));

    if (!__all(mx <= m_run + 11.0f)) {   // defer-max
      const float nm = fmaxf(m_run, mx);
      const float corr = exp2f(m_run - nm);
      m_run = nm;
      l_run *= corr;
#pragma unroll
      for (int dt = 0; dt < 2; ++dt)
#pragma unroll
        for (int i = 0; i < 16; ++i) o[dt][i] *= corr;
    }

    float rs = 0.f;
#pragma unroll
    for (int tt = 0; tt < 2; ++tt)
#pragma unroll
      for (int i = 0; i < 16; ++i) {
        float e = exp2f(s[tt][i] - m_run);
        s[tt][i] = e;
        rs += e;
      }
    rs += __shfl_xor(rs, 32);
    l_run += rs;

    // ---- P^T B-frags: 4 cvt_pk + 2 permlane32_swap per 16-token group ----
    // tokens held: A-pack = G + 4*hi + {0..3}, B-pack = G + 8 + 4*hi + {0..3}, G = g16*16.
    // permlane32_swap(vdst=A, vsrc=B) exchanges A.hi-lanes <-> B.lo-lanes:
    //   A' = {pk(G+0,1),pk(G+2,3) | pk(G+8,9),pk(G+10,11)}  (hi=0 | hi=1 lanes)
    //   B' = {pk(G+4,5),pk(G+6,7) | pk(G+12,13),pk(G+14,15)}
    // -> frag words {A0,A1,B0,B1} = B[k][q] for k = hi*8 + 0..7.  (m214/HK T12 order)
    union PU { int i[4]; bf16x8 h; };
    PU pb[4];
#pragma unroll
    for (int g16 = 0; g16 < 4; ++g16) {
      const int tt = g16 >> 1, rb = (g16 & 1) * 8;
      int A0, A1, B0, B1;
      float a0 = s[tt][rb + 0], a1 = s[tt][rb + 1], a2 = s[tt][rb + 2], a3 = s[tt][rb + 3];
      float b0 = s[tt][rb + 4], b1 = s[tt][rb + 5], b2 = s[tt][rb + 6], b3 = s[tt][rb + 7];
      asm("v_cvt_pk_bf16_f32 %0, %1, %2" : "=v"(A0) : "v"(a0), "v"(a1));
      asm("v_cvt_pk_bf16_f32 %0, %1, %2" : "=v"(A1) : "v"(a2), "v"(a3));
      asm("v_cvt_pk_bf16_f32 %0, %1, %2" : "=v"(B0) : "v"(b0), "v"(b1));
      asm("v_cvt_pk_bf16_f32 %0, %1, %2" : "=v"(B1) : "v"(b2), "v"(b3));
      asm("v_permlane32_swap_b32 %0, %1" : "+v"(A0), "+v"(B0));
      asm("v_permlane32_swap_b32 %0, %1" : "+v"(A1), "+v"(B1));
      pb[g16].i[0] = A0; pb[g16].i[1] = A1; pb[g16].i[2] = B0; pb[g16].i[3] = B1;
    }

    // ---- O^T += V^T * P^T ----
#pragma unroll
    for (int dt = 0; dt < 2; ++dt)
#pragma unroll
      for (int ks = 0; ks < 4; ++ks) {
        bf16x8 va = *(const bf16x8*)(Vbuf + (dt * 32 + ql) * 128 + (((ks * 2 + hi) ^ sx) * 16));
        o[dt] = __builtin_amdgcn_mfma_f32_32x32x16_bf16(va, pb[ks].h, o[dt], 0, 0, 0);
      }

    buf ^= 1;
  }

  // epilogue: O^T[d][q] -> AO[b*1024+q][h*64+d], d runs in groups of 4 consecutive
  const float inv_l = 1.0f / l_run;
  unsigned short* aorow = AO + (size_t)(b * 1024 + q0w + ql) * 768 + h * 64 + hi * 4;
#pragma unroll
  for (int dt = 0; dt < 2; ++dt)
#pragma unroll
    for (int p = 0; p < 4; ++p) {
      ushort4 vv;
      vv.x = f2bf(o[dt][4 * p + 0] * inv_l);
      vv.y = f2bf(o[dt][4 * p + 1] * inv_l);
      vv.z = f2bf(o[dt][4 * p + 2] * inv_l);
      vv.w = f2bf(o[dt][4 * p + 3] * inv_l);
      *(ushort4*)&aorow[dt * 32 + 8 * p] = vv;
    }
}

extern "C" void kernel_launch(void* const* d_in, const int* in_sizes, int n_in,
                              void* d_out, int out_size, void* d_ws, size_t ws_size,
                              hipStream_t stream) {
  const float* x      = (const float*)d_in[0];
  const float* w_qkv  = (const float*)d_in[1];
  const float* b_qkv  = (const float*)d_in[2];
  const float* w_proj = (const float*)d_in[3];
  const float* b_proj = (const float*)d_in[4];

  char* ws = (char*)d_ws;
  unsigned short* xb     = (unsigned short*)(ws);               // 25165824 B
  unsigned short* Qb     = (unsigned short*)(ws + 25165824);    // 25165824 B
  unsigned short* Kb     = (unsigned short*)(ws + 50331648);    // 25165824 B
  unsigned short* VTb    = (unsigned short*)(ws + 75497472);    // 25165824 B
  unsigned short* wqkvb  = (unsigned short*)(ws + 100663296);   // 3538944 B
  unsigned short* wprojb = (unsigned short*)(ws + 104202240);   // 1179648 B
  unsigned short* AO = xb;  // alias: xb dead after GEMM1

  f2bf_kernel<<<12288, 256, 0, stream>>>(x, xb, 3145728);
  f2bf_kernel<<<1728, 256, 0, stream>>>(w_qkv, wqkvb, 442368);
  f2bf_kernel<<<576, 256, 0, stream>>>(w_proj, wprojb, 147456);

  gemm_bt<0><<<dim3(18, 128), 256, 0, stream>>>(xb, wqkvb, b_qkv, (void*)Qb, Kb, VTb);
  attn_kernel<<<1536, 256, 0, stream>>>(Qb, Kb, VTb, AO);
  gemm_bt<1><<<dim3(6, 128), 256, 0, stream>>>(AO, wprojb, b_proj, d_out, nullptr, nullptr);
}

// Round 6
// 249.946 us; speedup vs baseline: 2.0378x; 1.1041x over previous
//
#include <hip/hip_runtime.h>

typedef short bf16x8 __attribute__((ext_vector_type(8)));
typedef float f32x4 __attribute__((ext_vector_type(4)));
typedef float f32x16 __attribute__((ext_vector_type(16)));

#define Q_PRESCALE 0.05205877485199535f        /* LOG2E/sqrt(768) */

__device__ __forceinline__ unsigned short f2bf(float f) {
  unsigned u = __float_as_uint(f);
  u += 0x7fffu + ((u >> 16) & 1u);   // round-to-nearest-even
  return (unsigned short)(u >> 16);
}

__device__ __forceinline__ void gload_lds16(const void* g, void* l) {
  __builtin_amdgcn_global_load_lds(
      (const __attribute__((address_space(1))) void*)g,
      (__attribute__((address_space(3))) void*)l, 16, 0, 0);
}

__global__ __launch_bounds__(256) void f2bf_kernel(const float* __restrict__ src,
                                                   unsigned short* __restrict__ dst,
                                                   int n4) {
  int i = blockIdx.x * blockDim.x + threadIdx.x;
  if (i < n4) {
    float4 v = ((const float4*)src)[i];
    ushort4 o;
    o.x = f2bf(v.x); o.y = f2bf(v.y); o.z = f2bf(v.z); o.w = f2bf(v.w);
    ((ushort4*)dst)[i] = o;
  }
}

// Permute w_qkv rows into c-major layout: dst row col' = c*768 + h*64 + d
// (orig row = h*192 + d*3 + c), converting fp32 -> bf16.
__global__ __launch_bounds__(256) void wqkv_perm_kernel(const float* __restrict__ src,
                                                        unsigned short* __restrict__ dst) {
  int i = blockIdx.x * blockDim.x + threadIdx.x;   // 2304 * 192
  int col = i / 192, i4 = i % 192;
  int c = col / 768, rem = col % 768;
  int h = rem >> 6, d = rem & 63;
  int orig = h * 192 + d * 3 + c;
  float4 v = ((const float4*)(src + (size_t)orig * 768))[i4];
  ushort4 o;
  o.x = f2bf(v.x); o.y = f2bf(v.y); o.z = f2bf(v.z); o.w = f2bf(v.w);
  ((ushort4*)(dst + (size_t)col * 768))[i4] = o;
}

// C = A[M][768] * B[N][768]^T, bf16 in, fp32 acc. 128x128 tile, BK=32, double-buffered
// LDS with row-pair XOR chunk swizzle (bank-conflict-free ds_read_b128).
// EPI=0: QKV epilogue, B is c-major permuted (tiles pure Q/K/V; V via in-LDS transpose).
// EPI=1: proj epilogue (bias, fp32 coalesced out).
// NT = tiles along N. Grid = 1D (NT * M/128), bijective XCD remap inside.
template<int EPI, int NT>
__global__ __launch_bounds__(256) void gemm_bt(
    const unsigned short* __restrict__ A,
    const unsigned short* __restrict__ B,
    const float* __restrict__ bias,
    void* __restrict__ out0,
    unsigned short* __restrict__ Kb,
    unsigned short* __restrict__ VTb) {
  constexpr int K = 768;
  __shared__ __align__(16) unsigned short smem[16384];   // 32 KB: A dbuf + B dbuf (vt aliases)

  const int tid = threadIdx.x;
  const int w = tid >> 6, lane = tid & 63;
  const int g = lane >> 4, qq = lane & 15;
  const int wr = w >> 1, wc = w & 1;

  // bijective XCD remap (gridDim.x % 8 == 0)
  const int nwg = gridDim.x, chunk = nwg >> 3;
  const int id = blockIdx.x;
  const int id2 = (id & 7) * chunk + (id >> 3);
  const int bx = id2 % NT, by = id2 / NT;
  const int rowb = by * 128;

  const unsigned short* Ab = A + (size_t)rowb * K;
  const unsigned short* Bb = B + (size_t)bx * 128 * K;

  f32x4 acc[4][4];
#pragma unroll
  for (int i = 0; i < 4; i++)
#pragma unroll
    for (int j = 0; j < 4; j++) acc[i][j] = (f32x4){0.f, 0.f, 0.f, 0.f};

  // staging: 512 chunks (16B) per matrix; thread stages chunks {tid, tid+256} of A and B.
  // chunk j: line=j>>3, slot=j&7; logical s=slot^(line&7); row=2*line+(s>>2); c=(s&3).
  const int j0 = tid, j1 = tid + 256;
  const int l0 = j0 >> 3, s0 = (j0 & 7) ^ (l0 & 7);
  const int l1 = j1 >> 3, s1 = (j1 & 7) ^ (l1 & 7);
  const size_t off0 = (size_t)(2 * l0 + (s0 >> 2)) * K + (s0 & 3) * 8;
  const size_t off1 = (size_t)(2 * l1 + (s1 >> 2)) * K + (s1 & 3) * 8;

  // fragment read byte-offsets (swizzled), invariant across K-steps
  int aoff[4], boff[4];
#pragma unroll
  for (int mi = 0; mi < 4; mi++) {
    int row = wr * 64 + mi * 16 + qq;
    aoff[mi] = (row >> 1) * 128 + (((g + (row & 1) * 4) ^ ((row >> 1) & 7)) * 16);
    row = wc * 64 + mi * 16 + qq;
    boff[mi] = (row >> 1) * 128 + (((g + (row & 1) * 4) ^ ((row >> 1) & 7)) * 16);
  }

  // prologue: stage tile 0 into buf 0
  gload_lds16(Ab + off0, &smem[j0 * 8]);
  gload_lds16(Ab + off1, &smem[j1 * 8]);
  gload_lds16(Bb + off0, &smem[8192 + j0 * 8]);
  gload_lds16(Bb + off1, &smem[8192 + j1 * 8]);
  asm volatile("s_waitcnt vmcnt(0)" ::: "memory");
  __syncthreads();

  int bo = 0;   // byte.. element offset of current buffer (0 or 4096)
  for (int t = 0; t < 24; ++t) {
    if (t < 23) {                       // stage next tile; stays in flight during compute
      const int k0 = (t + 1) * 32;
      const int nb = bo ^ 4096;
      gload_lds16(Ab + off0 + k0, &smem[nb + j0 * 8]);
      gload_lds16(Ab + off1 + k0, &smem[nb + j1 * 8]);
      gload_lds16(Bb + off0 + k0, &smem[8192 + nb + j0 * 8]);
      gload_lds16(Bb + off1 + k0, &smem[8192 + nb + j1 * 8]);
    }
    const char* Ap = (const char*)&smem[bo];
    const char* Bp = (const char*)&smem[8192 + bo];
    bf16x8 af[4], bfr[4];
#pragma unroll
    for (int mi = 0; mi < 4; mi++) af[mi] = *(const bf16x8*)(Ap + aoff[mi]);
#pragma unroll
    for (int ni = 0; ni < 4; ni++) bfr[ni] = *(const bf16x8*)(Bp + boff[ni]);
#pragma unroll
    for (int mi = 0; mi < 4; mi++)
#pragma unroll
      for (int ni = 0; ni < 4; ni++)
        acc[mi][ni] = __builtin_amdgcn_mfma_f32_16x16x32_bf16(af[mi], bfr[ni], acc[mi][ni], 0, 0, 0);
    __syncthreads();   // drains vmcnt too: next tile ready, safe to overwrite buf
    bo ^= 4096;
  }

  if (EPI == 0) {
    // c-major permuted B: tile class c = bx/6, heads h0 = (bx%6)*2 (+wc)
    const int c = bx / 6;
    const int h0 = (bx % 6) * 2;
    const int b = rowb >> 10, n0 = rowb & 1023;
    if (c < 2) {
      unsigned short* dst = (c == 0) ? (unsigned short*)out0 : Kb;
      const float scale = (c == 0) ? Q_PRESCALE : 1.0f;
      const int h = h0 + wc;
      const size_t bh = (size_t)(b * 12 + h);
#pragma unroll
      for (int ni = 0; ni < 4; ni++) {
        const int d = ni * 16 + qq;
        const float bv = bias[h * 192 + d * 3 + c];
#pragma unroll
        for (int mi = 0; mi < 4; mi++)
#pragma unroll
          for (int r = 0; r < 4; r++) {
            const int n = n0 + wr * 64 + mi * 16 + g * 4 + r;
            dst[(bh * 1024 + n) * 64 + d] = f2bf((acc[mi][ni][r] + bv) * scale);
          }
      }
    } else {
      // V: in-LDS transpose (vt aliases dead stage buffers), pad 136 to break banks
      unsigned short* vt = smem;   // [64][136] = 17408 B <= 32 KB
#pragma unroll
      for (int p = 0; p < 2; ++p) {
        __syncthreads();
        if (wc == p) {
#pragma unroll
          for (int ni = 0; ni < 4; ni++) {
            const int d = ni * 16 + qq;
            const float bv = bias[(h0 + p) * 192 + d * 3 + 2];
#pragma unroll
            for (int mi = 0; mi < 4; mi++) {
              ushort4 pk;
              pk.x = f2bf(acc[mi][ni][0] + bv);
              pk.y = f2bf(acc[mi][ni][1] + bv);
              pk.z = f2bf(acc[mi][ni][2] + bv);
              pk.w = f2bf(acc[mi][ni][3] + bv);
              *(ushort4*)&vt[d * 136 + wr * 64 + mi * 16 + g * 4] = pk;
            }
          }
        }
        __syncthreads();
        const size_t bhp = (size_t)(b * 12 + h0 + p);
        const int dd = tid >> 2;
#pragma unroll
        for (int j = 0; j < 4; ++j) {
          const int ch = (tid & 3) + j * 4;
          uint4 vv = *(const uint4*)&vt[dd * 136 + ch * 8];
          *(uint4*)&VTb[(bhp * 64 + dd) * 1024 + n0 + ch * 8] = vv;
        }
      }
    }
  } else {
    float* O = (float*)out0;
    const int colb = bx * 128 + wc * 64;
#pragma unroll
    for (int ni = 0; ni < 4; ni++) {
      const int col = colb + ni * 16 + qq;
      const float bv = bias[col];
#pragma unroll
      for (int mi = 0; mi < 4; mi++)
#pragma unroll
        for (int r = 0; r < 4; r++) {
          const int row = rowb + wr * 64 + mi * 16 + g * 4 + r;
          O[(size_t)row * 768 + col] = acc[mi][ni][r] + bv;
        }
    }
  }
}

// Flash attention: 4 waves x 32 q-rows = 128 q/block, KVBLK=64, 32x32x16 MFMA.
// (unchanged — verified in round 4)
__global__ __launch_bounds__(256) void attn_kernel(
    const unsigned short* __restrict__ Qb,
    const unsigned short* __restrict__ Kb,
    const unsigned short* __restrict__ VTb,
    unsigned short* __restrict__ AO) {
  __shared__ unsigned short Klds[2][4096];
  __shared__ unsigned short Vlds[2][4096];
  const int tid = threadIdx.x;
  const int w = tid >> 6, lane = tid & 63;
  const int ql = lane & 31, hi = lane >> 5;

  const int bid = blockIdx.x;
  const int xcd = bid & 7, jj = bid >> 3;
  const int bh = xcd * 24 + (jj >> 3);
  const int qb = jj & 7;
  const int b = bh / 12, h = bh % 12;
  const int q0w = qb * 128 + w * 32;

  const unsigned short* Qh = Qb + (size_t)bh * 65536;
  const unsigned short* Kh = Kb + (size_t)bh * 65536;
  const unsigned short* Vh = VTb + (size_t)bh * 65536;

  bf16x8 qf[4];
#pragma unroll
  for (int ks = 0; ks < 4; ++ks)
    qf[ks] = *(const bf16x8*)&Qh[(size_t)(q0w + ql) * 64 + ks * 16 + hi * 8];

  float m_run = -INFINITY, l_run = 0.f;
  f32x16 o[2];
#pragma unroll
  for (int dt = 0; dt < 2; ++dt)
#pragma unroll
    for (int i = 0; i < 16; ++i) o[dt][i] = 0.f;

  const int j0 = w * 64 + lane;
  const int r0 = j0 >> 3, s0 = j0 & 7;
  const int g0 = s0 ^ (r0 & 7) ^ ((r0 >> 2) & 6);
  const int r1 = r0 + 32;
  const int sx = (ql & 7) ^ ((ql >> 2) & 6);

  auto stage = [&](int sb, int t0) {
    gload_lds16(Kh + (size_t)(t0 + r0) * 64 + g0 * 8, &Klds[sb][j0 * 8]);
    gload_lds16(Kh + (size_t)(t0 + r1) * 64 + g0 * 8, &Klds[sb][j0 * 8 + 2048]);
    gload_lds16(Vh + (size_t)r0 * 1024 + t0 + g0 * 8, &Vlds[sb][j0 * 8]);
    gload_lds16(Vh + (size_t)r1 * 1024 + t0 + g0 * 8, &Vlds[sb][j0 * 8 + 2048]);
  };

  int buf = 0;
  stage(0, 0);

  for (int t = 0; t < 16; ++t) {
    asm volatile("s_waitcnt vmcnt(0)" ::: "memory");
    __syncthreads();
    if (t < 15) stage(buf ^ 1, (t + 1) * 64);

    const char* Kbuf = (const char*)&Klds[buf][0];
    const char* Vbuf = (const char*)&Vlds[buf][0];

    f32x16 s[2];
#pragma unroll
    for (int tt = 0; tt < 2; ++tt) {
#pragma unroll
      for (int i = 0; i < 16; ++i) s[tt][i] = 0.f;
#pragma unroll
      for (int ks = 0; ks < 4; ++ks) {
        bf16x8 ka = *(const bf16x8*)(Kbuf + (tt * 32 + ql) * 128 + (((ks * 2 + hi) ^ sx) * 16));
        s[tt] = __builtin_amdgcn_mfma_f32_32x32x16_bf16(ka, qf[ks], s[tt], 0, 0, 0);
      }
    }

    float mx = s[0][0];
#pragma unroll
    for (int i = 1; i < 16; ++i) mx = fmaxf(mx, s[0][i]);
#pragma unroll
    for (int i = 0; i < 16; ++i) mx = fmaxf(mx, s[1][i]);
    mx = fmaxf(mx, __shfl_xor(mx, 32));

    if (!__all(mx <= m_run + 11.0f)) {
      const float nm = fmaxf(m_run, mx);
      const float corr = exp2f(m_run - nm);
      m_run = nm;
      l_run *= corr;
#pragma unroll
      for (int dt = 0; dt < 2; ++dt)
#pragma unroll
        for (int i = 0; i < 16; ++i) o[dt][i] *= corr;
    }

    float rs = 0.f;
#pragma unroll
    for (int tt = 0; tt < 2; ++tt)
#pragma unroll
      for (int i = 0; i < 16; ++i) {
        float e = exp2f(s[tt][i] - m_run);
        s[tt][i] = e;
        rs += e;
      }
    rs += __shfl_xor(rs, 32);
    l_run += rs;

    union PU { int i[4]; bf16x8 h; };
    PU pb[4];
#pragma unroll
    for (int g16 = 0; g16 < 4; ++g16) {
      const int tt = g16 >> 1, rb = (g16 & 1) * 8;
      int A0, A1, B0, B1;
      float a0 = s[tt][rb + 0], a1 = s[tt][rb + 1], a2 = s[tt][rb + 2], a3 = s[tt][rb + 3];
      float b0 = s[tt][rb + 4], b1 = s[tt][rb + 5], b2 = s[tt][rb + 6], b3 = s[tt][rb + 7];
      asm("v_cvt_pk_bf16_f32 %0, %1, %2" : "=v"(A0) : "v"(a0), "v"(a1));
      asm("v_cvt_pk_bf16_f32 %0, %1, %2" : "=v"(A1) : "v"(a2), "v"(a3));
      asm("v_cvt_pk_bf16_f32 %0, %1, %2" : "=v"(B0) : "v"(b0), "v"(b1));
      asm("v_cvt_pk_bf16_f32 %0, %1, %2" : "=v"(B1) : "v"(b2), "v"(b3));
      asm("v_permlane32_swap_b32 %0, %1" : "+v"(A0), "+v"(B0));
      asm("v_permlane32_swap_b32 %0, %1" : "+v"(A1), "+v"(B1));
      pb[g16].i[0] = A0; pb[g16].i[1] = A1; pb[g16].i[2] = B0; pb[g16].i[3] = B1;
    }

#pragma unroll
    for (int dt = 0; dt < 2; ++dt)
#pragma unroll
      for (int ks = 0; ks < 4; ++ks) {
        bf16x8 va = *(const bf16x8*)(Vbuf + (dt * 32 + ql) * 128 + (((ks * 2 + hi) ^ sx) * 16));
        o[dt] = __builtin_amdgcn_mfma_f32_32x32x16_bf16(va, pb[ks].h, o[dt], 0, 0, 0);
      }

    buf ^= 1;
  }

  const float inv_l = 1.0f / l_run;
  unsigned short* aorow = AO + (size_t)(b * 1024 + q0w + ql) * 768 + h * 64 + hi * 4;
#pragma unroll
  for (int dt = 0; dt < 2; ++dt)
#pragma unroll
    for (int p = 0; p < 4; ++p) {
      ushort4 vv;
      vv.x = f2bf(o[dt][4 * p + 0] * inv_l);
      vv.y = f2bf(o[dt][4 * p + 1] * inv_l);
      vv.z = f2bf(o[dt][4 * p + 2] * inv_l);
      vv.w = f2bf(o[dt][4 * p + 3] * inv_l);
      *(ushort4*)&aorow[dt * 32 + 8 * p] = vv;
    }
}

extern "C" void kernel_launch(void* const* d_in, const int* in_sizes, int n_in,
                              void* d_out, int out_size, void* d_ws, size_t ws_size,
                              hipStream_t stream) {
  const float* x      = (const float*)d_in[0];
  const float* w_qkv  = (const float*)d_in[1];
  const float* b_qkv  = (const float*)d_in[2];
  const float* w_proj = (const float*)d_in[3];
  const float* b_proj = (const float*)d_in[4];

  char* ws = (char*)d_ws;
  unsigned short* xb     = (unsigned short*)(ws);               // 25165824 B
  unsigned short* Qb     = (unsigned short*)(ws + 25165824);    // 25165824 B
  unsigned short* Kb     = (unsigned short*)(ws + 50331648);    // 25165824 B
  unsigned short* VTb    = (unsigned short*)(ws + 75497472);    // 25165824 B
  unsigned short* wqkvb  = (unsigned short*)(ws + 100663296);   // 3538944 B (c-major permuted)
  unsigned short* wprojb = (unsigned short*)(ws + 104202240);   // 1179648 B
  unsigned short* AO = xb;  // alias: xb dead after GEMM1

  f2bf_kernel<<<12288, 256, 0, stream>>>(x, xb, 3145728);
  wqkv_perm_kernel<<<1728, 256, 0, stream>>>(w_qkv, wqkvb);
  f2bf_kernel<<<576, 256, 0, stream>>>(w_proj, wprojb, 147456);

  gemm_bt<0, 18><<<2304, 256, 0, stream>>>(xb, wqkvb, b_qkv, (void*)Qb, Kb, VTb);
  attn_kernel<<<1536, 256, 0, stream>>>(Qb, Kb, VTb, AO);
  gemm_bt<1, 6><<<768, 256, 0, stream>>>(AO, wprojb, b_proj, d_out, nullptr, nullptr);
}

// Round 8
// 247.958 us; speedup vs baseline: 2.0541x; 1.0080x over previous
//
#include <hip/hip_runtime.h>

typedef short bf16x8 __attribute__((ext_vector_type(8)));
typedef float f32x4 __attribute__((ext_vector_type(4)));
typedef float f32x16 __attribute__((ext_vector_type(16)));

#define Q_PRESCALE 0.05205877485199535f        /* LOG2E/sqrt(768) */

__device__ __forceinline__ unsigned short f2bf(float f) {
  unsigned u = __float_as_uint(f);
  u += 0x7fffu + ((u >> 16) & 1u);   // round-to-nearest-even
  return (unsigned short)(u >> 16);
}

__device__ __forceinline__ float fast_exp2(float x) {
  return __builtin_amdgcn_exp2f(x);   // v_exp_f32, compiler-visible (hazards handled)
}

__device__ __forceinline__ void gload_lds16(const void* g, void* l) {
  __builtin_amdgcn_global_load_lds(
      (const __attribute__((address_space(1))) void*)g,
      (__attribute__((address_space(3))) void*)l, 16, 0, 0);
}

__global__ __launch_bounds__(256) void f2bf_kernel(const float* __restrict__ src,
                                                   unsigned short* __restrict__ dst,
                                                   int n4) {
  int i = blockIdx.x * blockDim.x + threadIdx.x;
  if (i < n4) {
    float4 v = ((const float4*)src)[i];
    ushort4 o;
    o.x = f2bf(v.x); o.y = f2bf(v.y); o.z = f2bf(v.z); o.w = f2bf(v.w);
    ((ushort4*)dst)[i] = o;
  }
}

// Permute w_qkv rows into c-major layout: dst row col' = c*768 + h*64 + d
__global__ __launch_bounds__(256) void wqkv_perm_kernel(const float* __restrict__ src,
                                                        unsigned short* __restrict__ dst) {
  int i = blockIdx.x * blockDim.x + threadIdx.x;   // 2304 * 192
  int col = i / 192, i4 = i % 192;
  int c = col / 768, rem = col % 768;
  int h = rem >> 6, d = rem & 63;
  int orig = h * 192 + d * 3 + c;
  float4 v = ((const float4*)(src + (size_t)orig * 768))[i4];
  ushort4 o;
  o.x = f2bf(v.x); o.y = f2bf(v.y); o.z = f2bf(v.z); o.w = f2bf(v.w);
  ((ushort4*)(dst + (size_t)col * 768))[i4] = o;
}

// C = A[M][768] * B[N][768]^T, bf16 in, fp32 acc. 128x128 tile, BK=32, double-buffered
// swizzled LDS. (unchanged — verified round 6)
template<int EPI, int NT>
__global__ __launch_bounds__(256) void gemm_bt(
    const unsigned short* __restrict__ A,
    const unsigned short* __restrict__ B,
    const float* __restrict__ bias,
    void* __restrict__ out0,
    unsigned short* __restrict__ Kb,
    unsigned short* __restrict__ VTb) {
  constexpr int K = 768;
  __shared__ __align__(16) unsigned short smem[16384];

  const int tid = threadIdx.x;
  const int w = tid >> 6, lane = tid & 63;
  const int g = lane >> 4, qq = lane & 15;
  const int wr = w >> 1, wc = w & 1;

  const int nwg = gridDim.x, chunk = nwg >> 3;
  const int id = blockIdx.x;
  const int id2 = (id & 7) * chunk + (id >> 3);
  const int bx = id2 % NT, by = id2 / NT;
  const int rowb = by * 128;

  const unsigned short* Ab = A + (size_t)rowb * K;
  const unsigned short* Bb = B + (size_t)bx * 128 * K;

  f32x4 acc[4][4];
#pragma unroll
  for (int i = 0; i < 4; i++)
#pragma unroll
    for (int j = 0; j < 4; j++) acc[i][j] = (f32x4){0.f, 0.f, 0.f, 0.f};

  const int j0 = tid, j1 = tid + 256;
  const int l0 = j0 >> 3, s0 = (j0 & 7) ^ (l0 & 7);
  const int l1 = j1 >> 3, s1 = (j1 & 7) ^ (l1 & 7);
  const size_t off0 = (size_t)(2 * l0 + (s0 >> 2)) * K + (s0 & 3) * 8;
  const size_t off1 = (size_t)(2 * l1 + (s1 >> 2)) * K + (s1 & 3) * 8;

  int aoff[4], boff[4];
#pragma unroll
  for (int mi = 0; mi < 4; mi++) {
    int row = wr * 64 + mi * 16 + qq;
    aoff[mi] = (row >> 1) * 128 + (((g + (row & 1) * 4) ^ ((row >> 1) & 7)) * 16);
    row = wc * 64 + mi * 16 + qq;
    boff[mi] = (row >> 1) * 128 + (((g + (row & 1) * 4) ^ ((row >> 1) & 7)) * 16);
  }

  gload_lds16(Ab + off0, &smem[j0 * 8]);
  gload_lds16(Ab + off1, &smem[j1 * 8]);
  gload_lds16(Bb + off0, &smem[8192 + j0 * 8]);
  gload_lds16(Bb + off1, &smem[8192 + j1 * 8]);
  asm volatile("s_waitcnt vmcnt(0)" ::: "memory");
  __syncthreads();

  int bo = 0;
  for (int t = 0; t < 24; ++t) {
    if (t < 23) {
      const int k0 = (t + 1) * 32;
      const int nb = bo ^ 4096;
      gload_lds16(Ab + off0 + k0, &smem[nb + j0 * 8]);
      gload_lds16(Ab + off1 + k0, &smem[nb + j1 * 8]);
      gload_lds16(Bb + off0 + k0, &smem[8192 + nb + j0 * 8]);
      gload_lds16(Bb + off1 + k0, &smem[8192 + nb + j1 * 8]);
    }
    const char* Ap = (const char*)&smem[bo];
    const char* Bp = (const char*)&smem[8192 + bo];
    bf16x8 af[4], bfr[4];
#pragma unroll
    for (int mi = 0; mi < 4; mi++) af[mi] = *(const bf16x8*)(Ap + aoff[mi]);
#pragma unroll
    for (int ni = 0; ni < 4; ni++) bfr[ni] = *(const bf16x8*)(Bp + boff[ni]);
#pragma unroll
    for (int mi = 0; mi < 4; mi++)
#pragma unroll
      for (int ni = 0; ni < 4; ni++)
        acc[mi][ni] = __builtin_amdgcn_mfma_f32_16x16x32_bf16(af[mi], bfr[ni], acc[mi][ni], 0, 0, 0);
    __syncthreads();
    bo ^= 4096;
  }

  if (EPI == 0) {
    const int c = bx / 6;
    const int h0 = (bx % 6) * 2;
    const int b = rowb >> 10, n0 = rowb & 1023;
    if (c < 2) {
      unsigned short* dst = (c == 0) ? (unsigned short*)out0 : Kb;
      const float scale = (c == 0) ? Q_PRESCALE : 1.0f;
      const int h = h0 + wc;
      const size_t bh = (size_t)(b * 12 + h);
#pragma unroll
      for (int ni = 0; ni < 4; ni++) {
        const int d = ni * 16 + qq;
        const float bv = bias[h * 192 + d * 3 + c];
#pragma unroll
        for (int mi = 0; mi < 4; mi++)
#pragma unroll
          for (int r = 0; r < 4; r++) {
            const int n = n0 + wr * 64 + mi * 16 + g * 4 + r;
            dst[(bh * 1024 + n) * 64 + d] = f2bf((acc[mi][ni][r] + bv) * scale);
          }
      }
    } else {
      unsigned short* vt = smem;   // [64][136]
#pragma unroll
      for (int p = 0; p < 2; ++p) {
        __syncthreads();
        if (wc == p) {
#pragma unroll
          for (int ni = 0; ni < 4; ni++) {
            const int d = ni * 16 + qq;
            const float bv = bias[(h0 + p) * 192 + d * 3 + 2];
#pragma unroll
            for (int mi = 0; mi < 4; mi++) {
              ushort4 pk;
              pk.x = f2bf(acc[mi][ni][0] + bv);
              pk.y = f2bf(acc[mi][ni][1] + bv);
              pk.z = f2bf(acc[mi][ni][2] + bv);
              pk.w = f2bf(acc[mi][ni][3] + bv);
              *(ushort4*)&vt[d * 136 + wr * 64 + mi * 16 + g * 4] = pk;
            }
          }
        }
        __syncthreads();
        const size_t bhp = (size_t)(b * 12 + h0 + p);
        const int dd = tid >> 2;
#pragma unroll
        for (int j = 0; j < 4; ++j) {
          const int ch = (tid & 3) + j * 4;
          uint4 vv = *(const uint4*)&vt[dd * 136 + ch * 8];
          *(uint4*)&VTb[(bhp * 64 + dd) * 1024 + n0 + ch * 8] = vv;
        }
      }
    }
  } else {
    float* O = (float*)out0;
    const int colb = bx * 128 + wc * 64;
#pragma unroll
    for (int ni = 0; ni < 4; ni++) {
      const int col = colb + ni * 16 + qq;
      const float bv = bias[col];
#pragma unroll
      for (int mi = 0; mi < 4; mi++)
#pragma unroll
        for (int r = 0; r < 4; r++) {
          const int row = rowb + wr * 64 + mi * 16 + g * 4 + r;
          O[(size_t)row * 768 + col] = acc[mi][ni][r] + bv;
        }
    }
  }
}

// Flash attention: 4 waves x 32 q-rows, KVBLK=64, 32x32x16 MFMA.
// Round-8: keep round-7 structure (V^T global->reg, Vlds dropped, pairwise trees,
// fast exp2) but use the compiler-visible exp2 builtin and revert cross-half
// reductions to the verified __shfl_xor(·,32). pb path identical to rounds 4/6.
__global__ __launch_bounds__(256) void attn_kernel(
    const unsigned short* __restrict__ Qb,
    const unsigned short* __restrict__ Kb,
    const unsigned short* __restrict__ VTb,
    unsigned short* __restrict__ AO) {
  __shared__ unsigned short Klds[2][4096];
  const int tid = threadIdx.x;
  const int w = tid >> 6, lane = tid & 63;
  const int ql = lane & 31, hi = lane >> 5;

  const int bid = blockIdx.x;
  const int xcd = bid & 7, jj = bid >> 3;
  const int bh = xcd * 24 + (jj >> 3);
  const int qb = jj & 7;
  const int b = bh / 12, h = bh % 12;
  const int q0w = qb * 128 + w * 32;

  const unsigned short* Qh = Qb + (size_t)bh * 65536;
  const unsigned short* Kh = Kb + (size_t)bh * 65536;
  const unsigned short* Vh = VTb + (size_t)bh * 65536;

  bf16x8 qf[4];
#pragma unroll
  for (int ks = 0; ks < 4; ++ks)
    qf[ks] = *(const bf16x8*)&Qh[(size_t)(q0w + ql) * 64 + ks * 16 + hi * 8];

  float m_run = -INFINITY, l_run = 0.f;
  f32x16 o[2];
#pragma unroll
  for (int dt = 0; dt < 2; ++dt)
#pragma unroll
    for (int i = 0; i < 16; ++i) o[dt][i] = 0.f;

  // K staging: chunk j (16B): line=j>>3, slot=j&7; swizzled source chunk g0
  const int j0 = w * 64 + lane;
  const int r0 = j0 >> 3, s0 = j0 & 7;
  const int g0 = s0 ^ (r0 & 7) ^ ((r0 >> 2) & 6);
  const int kg0 = r0 * 64 + g0 * 8;          // element offset within K tile
  const int sx = (ql & 7) ^ ((ql >> 2) & 6); // reader swizzle bits

  int koff[2][4];
#pragma unroll
  for (int tt = 0; tt < 2; ++tt)
#pragma unroll
    for (int ks = 0; ks < 4; ++ks)
      koff[tt][ks] = (tt * 32 + ql) * 128 + (((ks * 2 + hi) ^ sx) * 16);
  int voff[2][4];
#pragma unroll
  for (int dt = 0; dt < 2; ++dt)
#pragma unroll
    for (int ks = 0; ks < 4; ++ks)
      voff[dt][ks] = (dt * 32 + ql) * 1024 + ks * 16 + hi * 8;

  // prologue: stage K tile 0
  gload_lds16(Kh + kg0, &Klds[0][j0 * 8]);
  gload_lds16(Kh + kg0 + 2048, &Klds[0][j0 * 8 + 2048]);

  int buf = 0;
  for (int t = 0; t < 16; ++t) {
    asm volatile("s_waitcnt vmcnt(0)" ::: "memory");
    __syncthreads();
    if (t < 15) {
      const unsigned short* Kn = Kh + (size_t)(t + 1) * 4096;
      gload_lds16(Kn + kg0, &Klds[buf ^ 1][j0 * 8]);
      gload_lds16(Kn + kg0 + 2048, &Klds[buf ^ 1][j0 * 8 + 2048]);
    }

    // V^T fragments -> registers (consumed after softmax; latency hidden)
    const unsigned short* Vt = Vh + t * 64;
    bf16x8 vf[2][4];
#pragma unroll
    for (int dt = 0; dt < 2; ++dt)
#pragma unroll
      for (int ks = 0; ks < 4; ++ks)
        vf[dt][ks] = *(const bf16x8*)&Vt[voff[dt][ks]];

    const char* Kbuf = (const char*)&Klds[buf][0];

    // ---- S^T = K * Q^T ----
    f32x16 s[2];
#pragma unroll
    for (int tt = 0; tt < 2; ++tt) {
#pragma unroll
      for (int i = 0; i < 16; ++i) s[tt][i] = 0.f;
#pragma unroll
      for (int ks = 0; ks < 4; ++ks) {
        bf16x8 ka = *(const bf16x8*)(Kbuf + koff[tt][ks]);
        s[tt] = __builtin_amdgcn_mfma_f32_32x32x16_bf16(ka, qf[ks], s[tt], 0, 0, 0);
      }
    }

    // ---- max: pairwise tree + shfl cross-half (verified) ----
    float m16[16];
#pragma unroll
    for (int i = 0; i < 16; ++i) m16[i] = fmaxf(s[0][i], s[1][i]);
    float m8[8];
#pragma unroll
    for (int i = 0; i < 8; ++i) m8[i] = fmaxf(m16[i], m16[i + 8]);
    float m4[4];
#pragma unroll
    for (int i = 0; i < 4; ++i) m4[i] = fmaxf(m8[i], m8[i + 4]);
    float mx = fmaxf(fmaxf(m4[0], m4[1]), fmaxf(m4[2], m4[3]));
    mx = fmaxf(mx, __shfl_xor(mx, 32));

    if (!__all(mx <= m_run + 11.0f)) {   // defer-max
      const float nm = fmaxf(m_run, mx);
      const float corr = fast_exp2(m_run - nm);
      m_run = nm;
      l_run *= corr;
#pragma unroll
      for (int dt = 0; dt < 2; ++dt)
#pragma unroll
        for (int i = 0; i < 16; ++i) o[dt][i] *= corr;
    }

    // ---- exp (v_exp_f32 via builtin) + sum tree + shfl cross-half ----
#pragma unroll
    for (int tt = 0; tt < 2; ++tt)
#pragma unroll
      for (int i = 0; i < 16; ++i) s[tt][i] = fast_exp2(s[tt][i] - m_run);
    float r16[16];
#pragma unroll
    for (int i = 0; i < 16; ++i) r16[i] = s[0][i] + s[1][i];
    float r8[8];
#pragma unroll
    for (int i = 0; i < 8; ++i) r8[i] = r16[i] + r16[i + 8];
    float r4[4];
#pragma unroll
    for (int i = 0; i < 4; ++i) r4[i] = r8[i] + r8[i + 4];
    float rs = (r4[0] + r4[1]) + (r4[2] + r4[3]);
    rs += __shfl_xor(rs, 32);
    l_run += rs;

    // ---- P^T B-frags: cvt_pk + permlane32_swap (verified rounds 4/6) ----
    union PU { int i[4]; bf16x8 h; };
    PU pb[4];
#pragma unroll
    for (int g16 = 0; g16 < 4; ++g16) {
      const int tt = g16 >> 1, rb = (g16 & 1) * 8;
      int A0, A1, B0, B1;
      float a0 = s[tt][rb + 0], a1 = s[tt][rb + 1], a2 = s[tt][rb + 2], a3 = s[tt][rb + 3];
      float b0 = s[tt][rb + 4], b1 = s[tt][rb + 5], b2 = s[tt][rb + 6], b3 = s[tt][rb + 7];
      asm("v_cvt_pk_bf16_f32 %0, %1, %2" : "=v"(A0) : "v"(a0), "v"(a1));
      asm("v_cvt_pk_bf16_f32 %0, %1, %2" : "=v"(A1) : "v"(a2), "v"(a3));
      asm("v_cvt_pk_bf16_f32 %0, %1, %2" : "=v"(B0) : "v"(b0), "v"(b1));
      asm("v_cvt_pk_bf16_f32 %0, %1, %2" : "=v"(B1) : "v"(b2), "v"(b3));
      asm("v_permlane32_swap_b32 %0, %1" : "+v"(A0), "+v"(B0));
      asm("v_permlane32_swap_b32 %0, %1" : "+v"(A1), "+v"(B1));
      pb[g16].i[0] = A0; pb[g16].i[1] = A1; pb[g16].i[2] = B0; pb[g16].i[3] = B1;
    }

    // ---- O^T += V^T * P^T (V from registers) ----
#pragma unroll
    for (int dt = 0; dt < 2; ++dt)
#pragma unroll
      for (int ks = 0; ks < 4; ++ks)
        o[dt] = __builtin_amdgcn_mfma_f32_32x32x16_bf16(vf[dt][ks], pb[ks].h, o[dt], 0, 0, 0);

    buf ^= 1;
  }

  const float inv_l = 1.0f / l_run;
  unsigned short* aorow = AO + (size_t)(b * 1024 + q0w + ql) * 768 + h * 64 + hi * 4;
#pragma unroll
  for (int dt = 0; dt < 2; ++dt)
#pragma unroll
    for (int p = 0; p < 4; ++p) {
      ushort4 vv;
      vv.x = f2bf(o[dt][4 * p + 0] * inv_l);
      vv.y = f2bf(o[dt][4 * p + 1] * inv_l);
      vv.z = f2bf(o[dt][4 * p + 2] * inv_l);
      vv.w = f2bf(o[dt][4 * p + 3] * inv_l);
      *(ushort4*)&aorow[dt * 32 + 8 * p] = vv;
    }
}

extern "C" void kernel_launch(void* const* d_in, const int* in_sizes, int n_in,
                              void* d_out, int out_size, void* d_ws, size_t ws_size,
                              hipStream_t stream) {
  const float* x      = (const float*)d_in[0];
  const float* w_qkv  = (const float*)d_in[1];
  const float* b_qkv  = (const float*)d_in[2];
  const float* w_proj = (const float*)d_in[3];
  const float* b_proj = (const float*)d_in[4];

  char* ws = (char*)d_ws;
  unsigned short* xb     = (unsigned short*)(ws);               // 25165824 B
  unsigned short* Qb     = (unsigned short*)(ws + 25165824);    // 25165824 B
  unsigned short* Kb     = (unsigned short*)(ws + 50331648);    // 25165824 B
  unsigned short* VTb    = (unsigned short*)(ws + 75497472);    // 25165824 B
  unsigned short* wqkvb  = (unsigned short*)(ws + 100663296);   // 3538944 B (c-major permuted)
  unsigned short* wprojb = (unsigned short*)(ws + 104202240);   // 1179648 B
  unsigned short* AO = xb;  // alias: xb dead after GEMM1

  f2bf_kernel<<<12288, 256, 0, stream>>>(x, xb, 3145728);
  wqkv_perm_kernel<<<1728, 256, 0, stream>>>(w_qkv, wqkvb);
  f2bf_kernel<<<576, 256, 0, stream>>>(w_proj, wprojb, 147456);

  gemm_bt<0, 18><<<2304, 256, 0, stream>>>(xb, wqkvb, b_qkv, (void*)Qb, Kb, VTb);
  attn_kernel<<<1536, 256, 0, stream>>>(Qb, Kb, VTb, AO);
  gemm_bt<1, 6><<<768, 256, 0, stream>>>(AO, wprojb, b_proj, d_out, nullptr, nullptr);
}